// Round 10
// baseline (152.133 us; speedup 1.0000x reference)
//
#include <hip/hip_runtime.h>
#include <hip/hip_bf16.h>

typedef __attribute__((ext_vector_type(8))) short short8;
typedef __attribute__((ext_vector_type(4))) float f32x4;

#define B_T 200
#define B_D 128

static __device__ __forceinline__ short f2bf(float f) {
  // round-to-nearest-even f32 -> bf16 (inputs are finite)
  unsigned u = __builtin_bit_cast(unsigned, f);
  u += 0x7fffu + ((u >> 16) & 1u);
  return (short)(u >> 16);
}
static __device__ __forceinline__ float bf2f(short s) {
  unsigned u = ((unsigned)(unsigned short)s) << 16;
  return __builtin_bit_cast(float, u);
}
static __device__ __forceinline__ short8 cvt8(f32x4 a, f32x4 b) {
  short8 t;
  t[0] = f2bf(a[0]); t[1] = f2bf(a[1]); t[2] = f2bf(a[2]); t[3] = f2bf(a[3]);
  t[4] = f2bf(b[0]); t[5] = f2bf(b[1]); t[6] = f2bf(b[2]); t[7] = f2bf(b[3]);
  return t;
}

// ---- prep 1: W1a/W1c -> fragment-linear bf16 tables (block-invariant, once).
// octet o (0..2047): j = o&127, ko = o>>7, elements k = ko*8+e.
__global__ __launch_bounds__(256) void ta_prep_w(const float* __restrict__ W1,
                                                 short* __restrict__ wfrag) {
  const int o = blockIdx.x * 256 + threadIdx.x;   // 2048 octets
  const int j = o & 127, k0 = (o >> 7) * 8;
  short8 ta, tc;
  #pragma unroll
  for (int e = 0; e < 8; ++e) {
    ta[e] = f2bf(W1[(size_t)(k0 + e) * B_D + j]);
    tc[e] = f2bf(W1[(size_t)(256 + k0 + e) * B_D + j]);
  }
  *(short8*)&wfrag[o * 8] = ta;
  *(short8*)&wfrag[16384 + o * 8] = tc;
}

// ---- prep 2: beta[b][j] = b1[j] + sum_k c[b][k]*W1b[k][j]. W1b staged in LDS
// once per block (8 b's) -> L2 traffic 268 MB -> 33 MB.
__global__ __launch_bounds__(256) void ta_prep_beta(const float* __restrict__ cand,
                                                    const float* __restrict__ W1,
                                                    const float* __restrict__ b1,
                                                    float* __restrict__ beta, int B) {
  __shared__ float w1b[B_D][B_D];   // 64 KB
  const int tid = threadIdx.x;
  #pragma unroll
  for (int i = 0; i < 16; ++i) {
    int v = i * 256 + tid;          // f32x4 index 0..4095
    ((f32x4*)w1b)[v] = ((const f32x4*)(W1 + 128 * B_D))[v];
  }
  __syncthreads();
  const int j = tid & 127, which = tid >> 7;
  const int b0 = blockIdx.x * 8;
  #pragma unroll
  for (int bi = 0; bi < 4; ++bi) {
    int b = b0 + bi * 2 + which;
    if (b < B) {
      const float* cb = cand + (size_t)b * B_D;
      float s0 = b1[j], s1 = 0.f, s2 = 0.f, s3 = 0.f;
      #pragma unroll 8
      for (int k = 0; k < 128; k += 4) {
        s0 = fmaf(cb[k    ], w1b[k    ][j], s0);
        s1 = fmaf(cb[k + 1], w1b[k + 1][j], s1);
        s2 = fmaf(cb[k + 2], w1b[k + 2][j], s2);
        s3 = fmaf(cb[k + 3], w1b[k + 3][j], s3);
      }
      beta[(size_t)b * B_D + j] = (s0 + s1) + (s2 + s3);
    }
  }
}

// ---- main: 256 threads / 4 waves, (256,4): 16 waves/CU, 4 blocks resident.
__global__ __launch_bounds__(256, 4)
void ta_fused(const float* __restrict__ x,      // [B,T,D]
              const float* __restrict__ cand,   // [B,D]
              const void*  __restrict__ maskp,  // [B,T] int32 or 1-byte bool
              const float* __restrict__ W1,     // [384,128]
              const float* __restrict__ b1,     // [128]
              const float* __restrict__ ap,     // [1]
              const float* __restrict__ W2,     // [128]
              const short* __restrict__ wfrag,  // [2][2048] bf16 octets (prep)
              const float* __restrict__ beta,   // [B,128] (prep)
              int use_ws,
              float* __restrict__ out)          // [B,D]
{
  // wbt fragment-linear bf16: element (k,j) at ((k>>3)*128 + j)*8 + (k&7).
  // Phase-C partials alias wbt (dead after phase A's last MFMA + barrier).
  __shared__ __align__(16) short wbt[B_D * B_D];   // 32 KB
  __shared__ float bpart[2][B_D];  // fallback-beta halves only
  __shared__ float w2_lds[B_D];
  __shared__ float scores[208];
  __shared__ float red[8];
  float (*part)[B_D] = (float (*)[B_D])wbt;        // phase-C alias

  const int b    = blockIdx.x;
  const int tid  = threadIdx.x;
  const int lane = tid & 63;
  const int wv   = tid >> 6;      // 0..3
  const int l15  = lane & 15;
  const int g    = lane >> 4;     // 0..3

  // ---- mask dtype probe: every wave scans the SAME 512 B -> block-consistent.
  int flag1b;
  {
    const unsigned char* mb = (const unsigned char*)maskp;
    unsigned long long v8 = *(const unsigned long long*)(mb + lane * 8);
    flag1b = __any((v8 & 0xFFFFFF00FFFFFF00ull) != 0ull);
  }
  bool mk = false;
  if (tid < B_T) {
    if (flag1b) mk = ((const unsigned char*)maskp)[(size_t)b * B_T + tid] != 0;
    else        mk = ((const int*)maskp)[(size_t)b * B_T + tid] != 0;
  }

  if (tid < B_D) w2_lds[tid] = W2[tid];

  // ---- phase 1: Wb = W1a + c (*) W1c -> wbt (from prep tables when available)
  const float* cb = cand + (size_t)b * B_D;
  if (use_ws) {
    #pragma unroll 2
    for (int it = 0; it < 8; ++it) {
      const int o = it * 256 + tid;       // 0..2047; o = ko*128 + j
      const int k0 = (o >> 7) * 8;        // wave-uniform
      short8 wa = *(const short8*)&wfrag[o * 8];
      short8 wc = *(const short8*)&wfrag[16384 + o * 8];
      short8 t;
      #pragma unroll
      for (int e = 0; e < 8; ++e)
        t[e] = f2bf(fmaf(cb[k0 + e], bf2f(wc[e]), bf2f(wa[e])));
      *(short8*)&wbt[o * 8] = t;          // consecutive-lane 16B -> conflict-free
    }
  } else {
    const int j = tid & 127, h = tid >> 7;
    #pragma unroll 2
    for (int it = 0; it < 8; ++it) {
      const int ko = it * 2 + h, k0 = ko * 8;
      short8 t;
      #pragma unroll
      for (int e = 0; e < 8; ++e) {
        float c  = cb[k0 + e];
        float wa = W1[(size_t)(k0 + e) * B_D + j];
        float wc = W1[(size_t)(256 + k0 + e) * B_D + j];
        t[e] = f2bf(fmaf(c, wc, wa));
      }
      *(short8*)&wbt[(ko * B_D + j) * 8] = t;
    }
    float s0 = (h == 0) ? b1[j] : 0.f, s1 = 0.f, s2 = 0.f, s3 = 0.f;
    const float* w1b = W1 + (size_t)(B_D + h * 64) * B_D + j;
    #pragma unroll 8
    for (int k = 0; k < 64; k += 4) {
      s0 = fmaf(cb[h * 64 + k    ], w1b[(size_t)(k    ) * B_D], s0);
      s1 = fmaf(cb[h * 64 + k + 1], w1b[(size_t)(k + 1) * B_D], s1);
      s2 = fmaf(cb[h * 64 + k + 2], w1b[(size_t)(k + 2) * B_D], s2);
      s3 = fmaf(cb[h * 64 + k + 3], w1b[(size_t)(k + 3) * B_D], s3);
    }
    bpart[h][j] = (s0 + s1) + (s2 + s3);
  }
  __syncthreads();   // the ONLY barrier before MFMA

  float betaL[8], w2L[8];
  #pragma unroll
  for (int nt = 0; nt < 8; ++nt) {
    int col = nt * 16 + l15;
    betaL[nt] = use_ws ? beta[(size_t)b * B_D + col] : (bpart[0][col] + bpart[1][col]);
    w2L[nt]   = w2_lds[col];
  }
  const float alpha = ap[0];

  // ---- phase A: per-tile {load x, cvt, MFMA, PReLU+W2 epilogue} -> scores.
#define TILE_SCORE(MT) do {                                                   \
    int row = (MT) * 16 + l15; if (row > B_T - 1) row = B_T - 1;              \
    const float* xr = x + ((size_t)b * B_T + row) * B_D + g * 8;              \
    f32x4 p0 = *(const f32x4*)(xr +  0), p1 = *(const f32x4*)(xr +   4);      \
    f32x4 p2 = *(const f32x4*)(xr + 32), p3 = *(const f32x4*)(xr +  36);      \
    f32x4 p4 = *(const f32x4*)(xr + 64), p5 = *(const f32x4*)(xr +  68);      \
    f32x4 p6 = *(const f32x4*)(xr + 96), p7 = *(const f32x4*)(xr + 100);      \
    short8 a0 = cvt8(p0, p1), a1 = cvt8(p2, p3);                              \
    short8 a2 = cvt8(p4, p5), a3 = cvt8(p6, p7);                              \
    float sc[4] = {0.f, 0.f, 0.f, 0.f};                                       \
    _Pragma("unroll")                                                         \
    for (int nt = 0; nt < 8; ++nt) {                                          \
      f32x4 acc = {0.f, 0.f, 0.f, 0.f};                                       \
      const short8* wp = (const short8*)wbt + g * B_D + nt * 16 + l15;        \
      acc = __builtin_amdgcn_mfma_f32_16x16x32_bf16(a0, wp[0],    acc, 0,0,0);\
      acc = __builtin_amdgcn_mfma_f32_16x16x32_bf16(a1, wp[512],  acc, 0,0,0);\
      acc = __builtin_amdgcn_mfma_f32_16x16x32_bf16(a2, wp[1024], acc, 0,0,0);\
      acc = __builtin_amdgcn_mfma_f32_16x16x32_bf16(a3, wp[1536], acc, 0,0,0);\
      _Pragma("unroll")                                                       \
      for (int r = 0; r < 4; ++r) {                                           \
        float h = acc[r] + betaL[nt];                                         \
        float p = (h >= 0.f) ? h : alpha * h;                                 \
        sc[r] += p * w2L[nt];                                                 \
      }                                                                       \
    }                                                                         \
    _Pragma("unroll")                                                         \
    for (int r = 0; r < 4; ++r) {                                             \
      float v = sc[r];                                                        \
      v += __shfl_xor(v, 1, 16); v += __shfl_xor(v, 2, 16);                   \
      v += __shfl_xor(v, 4, 16); v += __shfl_xor(v, 8, 16);                   \
      if (l15 == 0) scores[(MT) * 16 + g * 4 + r] = v;                        \
    }                                                                         \
  } while (0)

  TILE_SCORE(wv);
  TILE_SCORE(4 + wv);
  TILE_SCORE(8 + wv);
  if (wv == 0) TILE_SCORE(12);
#undef TILE_SCORE
  __syncthreads();

  // ---- phase B: masked softmax, 2 barriers; scores <- UNNORMALIZED e.
  {
    float s = (tid < B_T && mk) ? scores[tid] : -INFINITY;
    float v = s;
    #pragma unroll
    for (int m = 32; m >= 1; m >>= 1) v = fmaxf(v, __shfl_xor(v, m, 64));
    if (lane == 0) red[wv] = v;
    __syncthreads();
    float mx = fmaxf(fmaxf(red[0], red[1]), fmaxf(red[2], red[3]));
    float e = mk ? __expf(s - mx) : 0.f;
    float sv = e;
    #pragma unroll
    for (int m = 32; m >= 1; m >>= 1) sv += __shfl_xor(sv, m, 64);
    if (lane == 0) red[4 + wv] = sv;
    if (tid < 208) scores[tid] = e;     // tid in [200,208): e==0
    __syncthreads();                    // after this, wbt is dead -> part alias
  }

  // ---- phase C: part[p][:] = sum_{t in p-slice} e[t]*x[t,:] (L2/L3-hot),
  // contiguous f32x4 loads, 4-wide accumulator, 25 independent iterations.
  {
    const int d4 = (tid & 31) << 2;
    const int p  = tid >> 5;            // 0..7, t in [25p, 25p+25)
    const float* xc = x + ((size_t)b * B_T + p * 25) * B_D + d4;
    f32x4 acc = {0.f, 0.f, 0.f, 0.f};
    #pragma unroll 5
    for (int t = 0; t < 25; ++t) {
      f32x4 xv = *(const f32x4*)(xc + (size_t)t * B_D);
      float w = scores[p * 25 + t];
      acc[0] = fmaf(w, xv[0], acc[0]);
      acc[1] = fmaf(w, xv[1], acc[1]);
      acc[2] = fmaf(w, xv[2], acc[2]);
      acc[3] = fmaf(w, xv[3], acc[3]);
    }
    *(f32x4*)&part[p][d4] = acc;
  }
  __syncthreads();
  if (tid < B_D) {
    float Z = (red[4] + red[5]) + (red[6] + red[7]);
    float s = 0.f;
    #pragma unroll
    for (int p = 0; p < 8; ++p) s += part[p][tid];
    out[(size_t)b * B_D + tid] = s / Z;
  }
}

extern "C" void kernel_launch(void* const* d_in, const int* in_sizes, int n_in,
                              void* d_out, int out_size, void* d_ws, size_t ws_size,
                              hipStream_t stream) {
  const float* x    = (const float*)d_in[0];
  const float* cand = (const float*)d_in[1];
  const void*  mask = d_in[2];
  const float* W1   = (const float*)d_in[3];
  const float* b1   = (const float*)d_in[4];
  const float* a    = (const float*)d_in[5];
  const float* W2   = (const float*)d_in[6];
  float* out = (float*)d_out;
  const int B = in_sizes[1] / B_D;   // candidate is [B,128]

  short* wfrag = (short*)d_ws;                       // 64 KB (2×2048 octets)
  float* beta  = (float*)((char*)d_ws + 65536);      // B*128 f32
  const size_t need = 65536 + (size_t)B * B_D * sizeof(float);
  const int use_ws = (ws_size >= need) ? 1 : 0;

  if (use_ws) {
    ta_prep_w<<<8, 256, 0, stream>>>(W1, wfrag);
    ta_prep_beta<<<(B + 7) / 8, 256, 0, stream>>>(cand, W1, b1, beta, B);
  }
  ta_fused<<<B, 256, 0, stream>>>(x, cand, mask, W1, b1, a, W2,
                                  wfrag, beta, use_ws, out);
}